// Round 1
// baseline (430.041 us; speedup 1.0000x reference)
//
#include <hip/hip_runtime.h>

// x: [16, 2048, 2048] fp32; per-row (2048 elems) polynomial softmax.
// One block per row; 256 threads * 8 elements = 2048.

#define ROWLEN 2048
#define TPB    256

__global__ __launch_bounds__(TPB) void ckks_softmax_kernel(
    const float* __restrict__ x,
    const float* __restrict__ exp_c,   // 9 coeffs, power basis, exp_c[k] * x^k
    const float* __restrict__ inv_c,   // 5 coeffs
    const int*   __restrict__ iters_p, // single int (==3)
    float* __restrict__ out)
{
    const int row = blockIdx.x;
    const int tid = threadIdx.x;
    const size_t base = (size_t)row * ROWLEN;

    const float4* __restrict__ xv = (const float4*)(x + base);
    float4* __restrict__ ov       = (float4*)(out + base);

    // Uniform coefficient loads (compiler emits scalar loads; L2-resident).
    const float c0 = exp_c[0], c1 = exp_c[1], c2 = exp_c[2], c3 = exp_c[3],
                c4 = exp_c[4], c5 = exp_c[5], c6 = exp_c[6], c7 = exp_c[7],
                c8 = exp_c[8];

    // 8 elements per thread: two coalesced float4 loads.
    float4 a = xv[tid];
    float4 b = xv[tid + TPB];

    auto horner8 = [&](float v) -> float {
        float acc = c8;
        acc = fmaf(acc, v, c7);
        acc = fmaf(acc, v, c6);
        acc = fmaf(acc, v, c5);
        acc = fmaf(acc, v, c4);
        acc = fmaf(acc, v, c3);
        acc = fmaf(acc, v, c2);
        acc = fmaf(acc, v, c1);
        acc = fmaf(acc, v, c0);
        return acc;
    };

    float4 ea, eb;
    ea.x = horner8(a.x); ea.y = horner8(a.y); ea.z = horner8(a.z); ea.w = horner8(a.w);
    eb.x = horner8(b.x); eb.y = horner8(b.y); eb.z = horner8(b.z); eb.w = horner8(b.w);

    // Row-sum: thread-local, wave-64 shuffle, then cross-wave LDS combine.
    float local = ((ea.x + ea.y) + (ea.z + ea.w)) + ((eb.x + eb.y) + (eb.z + eb.w));
    #pragma unroll
    for (int off = 32; off > 0; off >>= 1)
        local += __shfl_down(local, off, 64);

    __shared__ float wsum[TPB / 64];
    const int wave = tid >> 6;
    if ((tid & 63) == 0) wsum[wave] = local;
    __syncthreads();
    const float s = (wsum[0] + wsum[1]) + (wsum[2] + wsum[3]);

    // Initial reciprocal guess: degree-4 Horner (redundant per-thread, cheap).
    float y = inv_c[4];
    y = fmaf(y, s, inv_c[3]);
    y = fmaf(y, s, inv_c[2]);
    y = fmaf(y, s, inv_c[1]);
    y = fmaf(y, s, inv_c[0]);

    // Newton-Raphson: y <- y * (2 - s*y). iterations read from device (graph-safe).
    const int iters = *iters_p;
    for (int i = 0; i < iters; ++i)
        y = y * (2.0f - s * y);

    ea.x *= y; ea.y *= y; ea.z *= y; ea.w *= y;
    eb.x *= y; eb.y *= y; eb.z *= y; eb.w *= y;

    ov[tid]       = ea;
    ov[tid + TPB] = eb;
}

extern "C" void kernel_launch(void* const* d_in, const int* in_sizes, int n_in,
                              void* d_out, int out_size, void* d_ws, size_t ws_size,
                              hipStream_t stream) {
    const float* x     = (const float*)d_in[0];
    const float* exp_c = (const float*)d_in[1];
    const float* inv_c = (const float*)d_in[2];
    const int*   iters = (const int*)d_in[3];
    float* out = (float*)d_out;

    const int n_rows = out_size / ROWLEN;  // 16 * 2048 = 32768
    ckks_softmax_kernel<<<n_rows, TPB, 0, stream>>>(x, exp_c, inv_c, iters, out);
}